// Round 1
// baseline (1521.233 us; speedup 1.0000x reference)
//
#include <hip/hip_runtime.h>
#include <hip/hip_bf16.h>
#include <stdint.h>

#define M_DIM 8192
#define K_DIM 4096
#define N_DIM 11008
#define BM 128
#define BN 128
#define BK 64

typedef __bf16 bf16x8 __attribute__((ext_vector_type(8)));
typedef float f32x4 __attribute__((ext_vector_type(4)));
typedef short short8 __attribute__((ext_vector_type(8)));

__device__ __forceinline__ ushort f32_to_bf16_rne(float f) {
    uint32_t u = __builtin_bit_cast(uint32_t, f);
    return (ushort)((u + 0x7fffu + ((u >> 16) & 1u)) >> 16);
}

// x fp32 -> bf16, 8 elems/thread
__global__ __launch_bounds__(256) void cvt_x_kernel(const float* __restrict__ x,
                                                    ushort* __restrict__ o, int n8) {
    int t = blockIdx.x * 256 + threadIdx.x;
    if (t >= n8) return;
    const float4* src = (const float4*)x + (size_t)t * 2;
    float4 a = src[0], b = src[1];
    union { ushort u[8]; short8 v; } r;
    r.u[0] = f32_to_bf16_rne(a.x); r.u[1] = f32_to_bf16_rne(a.y);
    r.u[2] = f32_to_bf16_rne(a.z); r.u[3] = f32_to_bf16_rne(a.w);
    r.u[4] = f32_to_bf16_rne(b.x); r.u[5] = f32_to_bf16_rne(b.y);
    r.u[6] = f32_to_bf16_rne(b.z); r.u[7] = f32_to_bf16_rne(b.w);
    *(short8*)(o + (size_t)t * 8) = r.v;
}

// weight int32 (harness widens int8->int32) -> bf16 (exact), 8 elems/thread
__global__ __launch_bounds__(256) void cvt_w_kernel(const int* __restrict__ w,
                                                    ushort* __restrict__ o, int n8) {
    int t = blockIdx.x * 256 + threadIdx.x;
    if (t >= n8) return;
    const int4* src = (const int4*)w + (size_t)t * 2;
    int4 a = src[0], b = src[1];
    union { ushort u[8]; short8 v; } r;
    r.u[0] = f32_to_bf16_rne((float)a.x); r.u[1] = f32_to_bf16_rne((float)a.y);
    r.u[2] = f32_to_bf16_rne((float)a.z); r.u[3] = f32_to_bf16_rne((float)a.w);
    r.u[4] = f32_to_bf16_rne((float)b.x); r.u[5] = f32_to_bf16_rne((float)b.y);
    r.u[6] = f32_to_bf16_rne((float)b.z); r.u[7] = f32_to_bf16_rne((float)b.w);
    *(short8*)(o + (size_t)t * 8) = r.v;
}

// C = A(MxK) * B(NxK)^T ; epilogue y = acc*scales[n] + bias[n]
// LDS tiles 128x64 bf16, XOR-swizzled in 8-elem k-groups: group stored at g^(row&7).
__global__ __launch_bounds__(256) void gemm_bf16_kernel(
    const ushort* __restrict__ A, const ushort* __restrict__ B,
    const float* __restrict__ scales, const float* __restrict__ bias,
    float* __restrict__ out) {
    __shared__ ushort sA[BM * BK];  // 16 KB
    __shared__ ushort sB[BN * BK];  // 16 KB

    const int t = threadIdx.x;
    const int l = t & 63;
    const int w = t >> 6;
    const int wm = w >> 1, wn = w & 1;

    const int m0 = blockIdx.y * BM;
    const int n0 = blockIdx.x * BN;

    // ---- staging source addresses (per thread covers 8 contiguous bf16) ----
    // flat LDS elem F = i*2048 + t*8 -> row r = i*32 + (t>>3), stored group gs = t&7
    // source k-group g = gs ^ (r&7)  (i*32 doesn't change r&7)
    const int r_base = t >> 3;
    const int g = (t & 7) ^ (r_base & 7);
    const ushort* aSrc = A + (size_t)(m0 + r_base) * K_DIM + g * 8;
    const ushort* bSrc = B + (size_t)(n0 + r_base) * K_DIM + g * 8;

    // ---- fragment LDS addresses ----
    const int rowA = wm * 64 + (l & 15);  // + i*16
    const int rowB = wn * 64 + (l & 15);  // + j*16
    // k-group for k-step kk: ks8 = (kk>>3) + (l>>4); stored at ks8 ^ (l&7)
    const int colg0 = (((l >> 4)) ^ (l & 7)) * 8;       // kk = 0
    const int colg1 = (((l >> 4) + 4) ^ (l & 7)) * 8;   // kk = 32

    f32x4 acc[4][4] = {};

    for (int kt = 0; kt < K_DIM / BK; ++kt) {
        const int k0 = kt * BK;
        __syncthreads();  // LDS free to overwrite
#pragma unroll
        for (int i = 0; i < 4; ++i) {
            __builtin_amdgcn_global_load_lds(
                (__attribute__((address_space(1))) void*)(aSrc + (size_t)i * 32 * K_DIM + k0),
                (__attribute__((address_space(3))) void*)(sA + i * 2048 + w * 512),
                16, 0, 0);
        }
#pragma unroll
        for (int i = 0; i < 4; ++i) {
            __builtin_amdgcn_global_load_lds(
                (__attribute__((address_space(1))) void*)(bSrc + (size_t)i * 32 * K_DIM + k0),
                (__attribute__((address_space(3))) void*)(sB + i * 2048 + w * 512),
                16, 0, 0);
        }
        __syncthreads();  // waits vmcnt(0): tiles ready

#pragma unroll
        for (int ks = 0; ks < 2; ++ks) {
            const int cg = ks ? colg1 : colg0;
            bf16x8 af[4], bfr[4];
#pragma unroll
            for (int i = 0; i < 4; ++i)
                af[i] = *(const bf16x8*)(sA + (rowA + i * 16) * 64 + cg);
#pragma unroll
            for (int j = 0; j < 4; ++j)
                bfr[j] = *(const bf16x8*)(sB + (rowB + j * 16) * 64 + cg);
#pragma unroll
            for (int i = 0; i < 4; ++i)
#pragma unroll
                for (int j = 0; j < 4; ++j)
                    acc[i][j] = __builtin_amdgcn_mfma_f32_16x16x32_bf16(
                        af[i], bfr[j], acc[i][j], 0, 0, 0);
        }
    }

    // ---- epilogue: y = acc * scales[n] + bias[n] ----
    const int mrow = m0 + wm * 64 + (l >> 4) * 4;
    const int ncol = n0 + wn * 64 + (l & 15);
#pragma unroll
    for (int j = 0; j < 4; ++j) {
        const int n = ncol + j * 16;
        const float s = scales[n];
        const float bz = bias[n];
#pragma unroll
        for (int i = 0; i < 4; ++i) {
            const int m = mrow + i * 16;
#pragma unroll
            for (int r2 = 0; r2 < 4; ++r2) {
                out[(size_t)(m + r2) * N_DIM + n] = acc[i][j][r2] * s + bz;
            }
        }
    }
}

extern "C" void kernel_launch(void* const* d_in, const int* in_sizes, int n_in,
                              void* d_out, int out_size, void* d_ws, size_t ws_size,
                              hipStream_t stream) {
    const float* x = (const float*)d_in[0];
    const int* wq = (const int*)d_in[1];
    const float* scales = (const float*)d_in[2];
    const float* bias = (const float*)d_in[3];
    float* out = (float*)d_out;

    const size_t x_elems = (size_t)M_DIM * K_DIM;       // 33,554,432
    const size_t w_elems = (size_t)N_DIM * K_DIM;       // 45,088,768
    const size_t need = (x_elems + w_elems) * sizeof(ushort);
    if (ws_size < need) return;  // workspace too small — fail loudly via mismatch

    ushort* xb = (ushort*)d_ws;
    ushort* wb = xb + x_elems;

    cvt_x_kernel<<<dim3((int)(x_elems / 8 / 256)), dim3(256), 0, stream>>>(x, xb, (int)(x_elems / 8));
    cvt_w_kernel<<<dim3((int)(w_elems / 8 / 256)), dim3(256), 0, stream>>>(wq, wb, (int)(w_elems / 8));

    gemm_bf16_kernel<<<dim3(N_DIM / BN, M_DIM / BM), dim3(256), 0, stream>>>(
        xb, wb, scales, bias, out);
}